// Round 1
// baseline (75.151 us; speedup 1.0000x reference)
//
#include <hip/hip_runtime.h>
#include <math.h>

#define N_NODES 100000
#define EMB_DIM 128
#define HALF    64
#define N_EDGES 500000
#define N_REL   16

// Kernel 1: cos/sin table, 16 relations x 64 phases. 8 KB total in d_ws.
__global__ void build_trig_table(const float* __restrict__ rel_emb,
                                 float* __restrict__ ctab,
                                 float* __restrict__ stab) {
    int idx = blockIdx.x * blockDim.x + threadIdx.x;
    if (idx < N_REL * HALF) {
        float p = rel_emb[idx];
        ctab[idx] = cosf(p);
        stab[idx] = sinf(p);
    }
}

// Kernel 2: one 16-lane group per edge, 4 dims per lane via float4.
// Four partial sums (|h|^2, |t|^2, h.t, rot(h).t) reduced in one butterfly;
// scores assembled algebraically:
//   dist^2 = nh*rnh^2 + nt*rnt^2 - 2*rnh*rnt*cross + eps
__global__ __launch_bounds__(256) void rotate_edge_kernel(
    const float* __restrict__ emb,
    const int* __restrict__ eidx,    // [2][N_EDGES]
    const int* __restrict__ rtype,   // [N_EDGES]
    const float* __restrict__ ctab,
    const float* __restrict__ stab,
    float* __restrict__ out)
{
    int e   = (blockIdx.x * blockDim.x + threadIdx.x) >> 4;  // edge id
    int sub = threadIdx.x & 15;                              // lane in group
    if (e >= N_EDGES) return;

    int hidx = eidx[e];
    int tidx = eidx[N_EDGES + e];
    int r    = rtype[e];

    const float4* h4 = (const float4*)(emb + (size_t)hidx * EMB_DIM);
    const float4* t4 = (const float4*)(emb + (size_t)tidx * EMB_DIM);
    float4 hre = h4[sub];        // dims 4*sub .. 4*sub+3   (real half)
    float4 him = h4[16 + sub];   // dims 64+4*sub ..        (imag half)
    float4 tre = t4[sub];
    float4 tim = t4[16 + sub];

    const float4* c4p = (const float4*)(ctab + r * HALF);
    const float4* s4p = (const float4*)(stab + r * HALF);
    float4 c = c4p[sub];
    float4 s = s4p[sub];

    float nh = 0.f, nt = 0.f, dt = 0.f, cx = 0.f;
#define ACC(K) {                                            \
        float a = hre.K, b = him.K, u = tre.K, v = tim.K;   \
        float cc = c.K, ss = s.K;                           \
        nh += a*a + b*b;                                    \
        nt += u*u + v*v;                                    \
        dt += a*u + b*v;                                    \
        float rr = a*cc - b*ss;                             \
        float ri = a*ss + b*cc;                             \
        cx += rr*u + ri*v;                                  \
    }
    ACC(x) ACC(y) ACC(z) ACC(w)
#undef ACC

    // reduce 4 sums across the 16-lane group (xor masks stay in-group)
    for (int m = 8; m >= 1; m >>= 1) {
        nh += __shfl_xor(nh, m);
        nt += __shfl_xor(nt, m);
        dt += __shfl_xor(dt, m);
        cx += __shfl_xor(cx, m);
    }

    if (sub == 0) {
        float rnh = 1.0f / fmaxf(sqrtf(nh), 1e-12f);
        float rnt = 1.0f / fmaxf(sqrtf(nt), 1e-12f);
        float dot_score = dt * rnh * rnt * (1.0f / (float)EMB_DIM) - 1.0f;
        float d2 = nh*rnh*rnh + nt*rnt*rnt - 2.0f*rnh*rnt*cx + 1e-8f;
        float rot_score = -sqrtf(d2);
        bool sym = (r == 0) || (r == 2) || (r == 4) || (r == 6);
        out[e] = sym ? dot_score : rot_score;
    }
}

extern "C" void kernel_launch(void* const* d_in, const int* in_sizes, int n_in,
                              void* d_out, int out_size, void* d_ws, size_t ws_size,
                              hipStream_t stream) {
    const float* emb   = (const float*)d_in[0];
    const float* rel   = (const float*)d_in[1];
    const int*   eidx  = (const int*)d_in[2];
    const int*   rtype = (const int*)d_in[3];
    float*       out   = (float*)d_out;

    float* ctab = (float*)d_ws;                 // 16*64 f32 = 4 KB
    float* stab = ctab + N_REL * HALF;          // next 4 KB

    build_trig_table<<<(N_REL * HALF + 255) / 256, 256, 0, stream>>>(rel, ctab, stab);

    int blocks = (N_EDGES * 16 + 255) / 256;    // 16 lanes per edge
    rotate_edge_kernel<<<blocks, 256, 0, stream>>>(emb, eidx, rtype, ctab, stab, out);
}

// Round 2
// 59.948 us; speedup vs baseline: 1.2536x; 1.2536x over previous
//
#include <hip/hip_runtime.h>
#include <hip/hip_fp16.h>
#include <math.h>

#define N_NODES 100000
#define EMB_DIM 128
#define HALF    64
#define N_EDGES 500000
#define N_REL   16

// ---------------------------------------------------------------------------
// Kernel A: trig table, interleaved (cos,sin) pairs per dim. 16 rel x 64 dims.
// trig[r*128 + 2d] = cos(phase), trig[r*128 + 2d + 1] = sin(phase). 8 KB.
__global__ void build_trig_interleaved(const float* __restrict__ rel_emb,
                                       float* __restrict__ trig) {
    int idx = blockIdx.x * blockDim.x + threadIdx.x;
    if (idx < N_REL * HALF) {
        int r = idx >> 6, d = idx & 63;
        float p = rel_emb[idx];
        trig[r * 128 + 2 * d]     = cosf(p);
        trig[r * 128 + 2 * d + 1] = sinf(p);
    }
}

// ---------------------------------------------------------------------------
// Kernel B: normalize each node row once, store fp16 interleaved (re,im)
// pairs: tab_u32[row*64 + d] = half2(x[d]/n, x[d+64]/n). Row = 256 B.
// One wave per row; lane d handles complex dim d.
__global__ __launch_bounds__(256) void normalize_fp16(
    const float* __restrict__ emb, unsigned int* __restrict__ tab) {
    int row  = blockIdx.x * 4 + (threadIdx.x >> 6);
    int lane = threadIdx.x & 63;
    if (row >= N_NODES) return;
    const float* rp = emb + (size_t)row * EMB_DIM;
    float a = rp[lane];
    float b = rp[lane + HALF];
    float p = a * a + b * b;
    for (int m = 32; m >= 1; m >>= 1) p += __shfl_xor(p, m);
    float rn = 1.0f / fmaxf(sqrtf(p), 1e-12f);
    __half2 hv = __floats2half2_rn(a * rn, b * rn);
    tab[(size_t)row * 64 + lane] = *reinterpret_cast<unsigned int*>(&hv);
}

__device__ __forceinline__ float2 u2f2(unsigned int u) {
    __half2 h = *reinterpret_cast<const __half2*>(&u);
    return __half22float2(h);
}

// ---------------------------------------------------------------------------
// Kernel C: 16 lanes per edge. Each lane loads ONE uint4 per row = 4 complex
// dims (whole 128-dim row = 256 B = one coalesced 16-lane request).
// Unit-norm rows => dist^2 = 2 - 2*cross; dot_score = dot/128 - 1.
__global__ __launch_bounds__(256) void rotate_edge_fp16(
    const unsigned int* __restrict__ tab,
    const float* __restrict__ trig,
    const int* __restrict__ eidx,
    const int* __restrict__ rtype,
    float* __restrict__ out)
{
    int e   = (blockIdx.x * blockDim.x + threadIdx.x) >> 4;
    int sub = threadIdx.x & 15;
    if (e >= N_EDGES) return;

    int hidx = eidx[e];
    int tidx = eidx[N_EDGES + e];
    int r    = rtype[e];

    uint4 hv = ((const uint4*)(tab + (size_t)hidx * 64))[sub];
    uint4 tv = ((const uint4*)(tab + (size_t)tidx * 64))[sub];
    const float4* cp = (const float4*)(trig + r * 128);
    float4 c0 = cp[2 * sub];       // pairs (c,s) for dims 4*sub, 4*sub+1
    float4 c1 = cp[2 * sub + 1];   // pairs (c,s) for dims 4*sub+2, 4*sub+3

    float dot = 0.f, cx = 0.f;
#define PAIR(HU, TU, CC, SS) {                               \
        float2 h2 = u2f2(HU);                                \
        float2 t2 = u2f2(TU);                                \
        dot += h2.x * t2.x + h2.y * t2.y;                    \
        float rr = h2.x * (CC) - h2.y * (SS);                \
        float ri = h2.x * (SS) + h2.y * (CC);                \
        cx += rr * t2.x + ri * t2.y;                         \
    }
    PAIR(hv.x, tv.x, c0.x, c0.y)
    PAIR(hv.y, tv.y, c0.z, c0.w)
    PAIR(hv.z, tv.z, c1.x, c1.y)
    PAIR(hv.w, tv.w, c1.z, c1.w)
#undef PAIR

    for (int m = 8; m >= 1; m >>= 1) {
        dot += __shfl_xor(dot, m);
        cx  += __shfl_xor(cx, m);
    }

    if (sub == 0) {
        float dot_score = dot * (1.0f / (float)EMB_DIM) - 1.0f;
        float d2 = fmaxf(2.0f - 2.0f * cx, 0.0f) + 1e-8f;
        float rot_score = -sqrtf(d2);
        bool sym = (r == 0) | (r == 2) | (r == 4) | (r == 6);
        out[e] = sym ? dot_score : rot_score;
    }
}

// ---------------------------------------------------------------------------
// Fallback (proven R1 path) if d_ws can't hold the 25.6 MB fp16 table.
__global__ void build_trig_table(const float* __restrict__ rel_emb,
                                 float* __restrict__ ctab,
                                 float* __restrict__ stab) {
    int idx = blockIdx.x * blockDim.x + threadIdx.x;
    if (idx < N_REL * HALF) {
        float p = rel_emb[idx];
        ctab[idx] = cosf(p);
        stab[idx] = sinf(p);
    }
}

__global__ __launch_bounds__(256) void rotate_edge_fp32(
    const float* __restrict__ emb,
    const int* __restrict__ eidx,
    const int* __restrict__ rtype,
    const float* __restrict__ ctab,
    const float* __restrict__ stab,
    float* __restrict__ out)
{
    int e   = (blockIdx.x * blockDim.x + threadIdx.x) >> 4;
    int sub = threadIdx.x & 15;
    if (e >= N_EDGES) return;

    int hidx = eidx[e];
    int tidx = eidx[N_EDGES + e];
    int r    = rtype[e];

    const float4* h4 = (const float4*)(emb + (size_t)hidx * EMB_DIM);
    const float4* t4 = (const float4*)(emb + (size_t)tidx * EMB_DIM);
    float4 hre = h4[sub], him = h4[16 + sub];
    float4 tre = t4[sub], tim = t4[16 + sub];
    float4 c = ((const float4*)(ctab + r * HALF))[sub];
    float4 s = ((const float4*)(stab + r * HALF))[sub];

    float nh = 0.f, nt = 0.f, dt = 0.f, cx = 0.f;
#define ACC(K) {                                            \
        float a = hre.K, b = him.K, u = tre.K, v = tim.K;   \
        float cc = c.K, ss = s.K;                           \
        nh += a*a + b*b;                                    \
        nt += u*u + v*v;                                    \
        dt += a*u + b*v;                                    \
        float rr = a*cc - b*ss;                             \
        float ri = a*ss + b*cc;                             \
        cx += rr*u + ri*v;                                  \
    }
    ACC(x) ACC(y) ACC(z) ACC(w)
#undef ACC

    for (int m = 8; m >= 1; m >>= 1) {
        nh += __shfl_xor(nh, m);
        nt += __shfl_xor(nt, m);
        dt += __shfl_xor(dt, m);
        cx += __shfl_xor(cx, m);
    }

    if (sub == 0) {
        float rnh = 1.0f / fmaxf(sqrtf(nh), 1e-12f);
        float rnt = 1.0f / fmaxf(sqrtf(nt), 1e-12f);
        float dot_score = dt * rnh * rnt * (1.0f / (float)EMB_DIM) - 1.0f;
        float d2 = nh*rnh*rnh + nt*rnt*rnt - 2.0f*rnh*rnt*cx + 1e-8f;
        float rot_score = -sqrtf(d2);
        bool sym = (r == 0) | (r == 2) | (r == 4) | (r == 6);
        out[e] = sym ? dot_score : rot_score;
    }
}

// ---------------------------------------------------------------------------
extern "C" void kernel_launch(void* const* d_in, const int* in_sizes, int n_in,
                              void* d_out, int out_size, void* d_ws, size_t ws_size,
                              hipStream_t stream) {
    const float* emb   = (const float*)d_in[0];
    const float* rel   = (const float*)d_in[1];
    const int*   eidx  = (const int*)d_in[2];
    const int*   rtype = (const int*)d_in[3];
    float*       out   = (float*)d_out;

    const size_t trig_bytes = (size_t)N_REL * 128 * sizeof(float);  // 8 KB
    const size_t tab_bytes  = (size_t)N_NODES * 64 * sizeof(unsigned int); // 25.6 MB
    const int edge_blocks = (N_EDGES * 16 + 255) / 256;

    if (ws_size >= trig_bytes + tab_bytes) {
        float* trig        = (float*)d_ws;
        unsigned int* tab  = (unsigned int*)((char*)d_ws + trig_bytes);

        build_trig_interleaved<<<(N_REL * HALF + 255) / 256, 256, 0, stream>>>(rel, trig);
        normalize_fp16<<<(N_NODES + 3) / 4, 256, 0, stream>>>(emb, tab);
        rotate_edge_fp16<<<edge_blocks, 256, 0, stream>>>(tab, trig, eidx, rtype, out);
    } else {
        float* ctab = (float*)d_ws;
        float* stab = ctab + N_REL * HALF;
        build_trig_table<<<(N_REL * HALF + 255) / 256, 256, 0, stream>>>(rel, ctab, stab);
        rotate_edge_fp32<<<edge_blocks, 256, 0, stream>>>(emb, eidx, rtype, ctab, stab, out);
    }
}